// Round 4
// baseline (19957.101 us; speedup 1.0000x reference)
//
#include <hip/hip_runtime.h>
#include <hip/hip_cooperative_groups.h>

namespace cg = cooperative_groups;

#define Bb 8
#define Ss 4096
#define Dd 512
#define Hh 1024
#define CSc 64
#define NCn 64
#define MROW 512  // Bb*CSc
#define NB 256    // persistent grid blocks

typedef unsigned short ushort_t;
typedef short s8v __attribute__((ext_vector_type(8)));
typedef unsigned short u8v __attribute__((ext_vector_type(8)));
typedef float f4v __attribute__((ext_vector_type(4)));

enum { PH_H1=0, PH_PRED, PH_D1, PH_UPD1, PH_UPD2, PH_H1Q, PH_R, PH_OUTC };

struct Ptrs {
  const float *x, *Wk, *Wv, *Wq, *Wout, *W1, *W2;
  ushort_t *kbuf, *vbuf, *qbuf, *rbuf;
  ushort_t *h1, *a1, *d1b, *d2b;
  float *Wd1a, *Wd1b, *Wd2a, *Wd2b, *M1, *M2;
  float *gates;
  float *out;
};

__device__ __forceinline__ float b2f(ushort_t u){
  union { unsigned int i; float f; } c; c.i = ((unsigned int)u) << 16; return c.f;
}
__device__ __forceinline__ ushort_t f2b(float f){
  union { float f; unsigned int i; } c; c.f = f;
  unsigned int i = c.i;
  i += 0x7fffu + ((i >> 16) & 1u);   // RTNE
  return (ushort_t)(i >> 16);
}
__device__ __forceinline__ float sig_(float v){ return 1.0f/(1.0f+__expf(-v)); }
__device__ __forceinline__ float silu_(float v){ return v*sig_(v); }
__device__ __forceinline__ float dsilu_(float v){ float s=sig_(v); return s*(1.0f + v*(1.0f-s)); }
__device__ __forceinline__ float clip1_(float v){ return fminf(fmaxf(v,-1.0f),1.0f); }
__device__ __forceinline__ size_t cidx(int m, int d, int nc){
  return ((size_t)((m>>6)*Ss) + nc*CSc + (m&63))*Dd + d;
}

// ============ one 32x64 output tile, 4 waves (2m x 2n), BK=32, bf16 MFMA =========
template<int PHASE, int KD>
__device__ void do_tile(const Ptrs& p, int nc, int tm, int tn,
                        const float* Wdb, const float* Wdold, float* Wdnew,
                        ushort_t* As, ushort_t* Bs)
{
  constexpr int STR = 40;  // shorts; 80B rows, 16B aligned
  const int tid = threadIdx.x;
  const int m0 = tm*32, n0 = tn*64;
  const int wave = tid>>6, lane = tid&63;
  const int wm = wave&1, wn = wave>>1;
  const int quad = lane>>4, l16 = lane&15;
  f4v acc0 = {0.f,0.f,0.f,0.f}, acc1 = {0.f,0.f,0.f,0.f};

  for (int k0=0; k0<KD; k0+=32){
    // ---- stage A: 32 rows x 32 k (threads 0..127) ----
    if (tid < 128){
      if constexpr (PHASE==PH_UPD1 || PHASE==PH_UPD2){
        int kk = tid>>2, mm0 = (tid&3)*8;
        const ushort_t* src; int stride;
        if constexpr (PHASE==PH_UPD1){ src=p.d1b; stride=Hh; } else { src=p.d2b; stride=Dd; }
        u8v v = *(const u8v*)&src[(size_t)(k0+kk)*stride + m0+mm0];
        #pragma unroll
        for (int j=0;j<8;j++) As[(mm0+j)*STR+kk] = v[j];
      } else {
        int mm = tid>>2, kk0 = (tid&3)*8;
        const ushort_t* s;
        if constexpr (PHASE==PH_H1)        s = &p.kbuf[cidx(m0+mm, k0+kk0, nc)];
        else if constexpr (PHASE==PH_H1Q)  s = &p.qbuf[cidx(m0+mm, k0+kk0, nc)];
        else if constexpr (PHASE==PH_PRED) s = &p.a1[(size_t)(m0+mm)*Hh + k0+kk0];
        else if constexpr (PHASE==PH_R)    s = &p.d1b[(size_t)(m0+mm)*Hh + k0+kk0];
        else if constexpr (PHASE==PH_D1)   s = &p.d2b[(size_t)(m0+mm)*Dd + k0+kk0];
        else /*PH_OUTC*/                   s = &p.rbuf[(size_t)(m0+mm)*Dd + k0+kk0];
        *(u8v*)&As[mm*STR+kk0] = *(const u8v*)s;
      }
    }
    // ---- stage B: Bs[nn][kk] = B[k][n], 64 n-rows x 32 k (all 256 threads) ----
    if constexpr (PHASE==PH_D1){
      int kk = tid>>3, nn0 = (tid&7)*8;
      size_t off = (size_t)(k0+kk)*Hh + n0+nn0;
      float4 a0=*(const float4*)&p.W2[off], a1_=*(const float4*)&p.W2[off+4];
      float4 b0=*(const float4*)&Wdb[off],  b1_=*(const float4*)&Wdb[off+4];
      Bs[(nn0+0)*STR+kk]=f2b(a0.x+b0.x); Bs[(nn0+1)*STR+kk]=f2b(a0.y+b0.y);
      Bs[(nn0+2)*STR+kk]=f2b(a0.z+b0.z); Bs[(nn0+3)*STR+kk]=f2b(a0.w+b0.w);
      Bs[(nn0+4)*STR+kk]=f2b(a1_.x+b1_.x); Bs[(nn0+5)*STR+kk]=f2b(a1_.y+b1_.y);
      Bs[(nn0+6)*STR+kk]=f2b(a1_.z+b1_.z); Bs[(nn0+7)*STR+kk]=f2b(a1_.w+b1_.w);
    } else if constexpr (PHASE==PH_UPD1){
      int kk = tid>>3, nn0 = (tid&7)*8;
      u8v v = *(const u8v*)&p.kbuf[cidx(k0+kk, n0+nn0, nc)];
      #pragma unroll
      for (int j=0;j<8;j++) Bs[(nn0+j)*STR+kk] = v[j];
    } else if constexpr (PHASE==PH_UPD2){
      int kk = tid>>3, nn0 = (tid&7)*8;
      u8v v = *(const u8v*)&p.a1[(size_t)(k0+kk)*Hh + n0+nn0];
      #pragma unroll
      for (int j=0;j<8;j++) Bs[(nn0+j)*STR+kk] = v[j];
    } else {
      int nn = tid>>2, kk0 = (tid&3)*8;
      const float *s1, *s2 = nullptr;
      if constexpr (PHASE==PH_H1 || PHASE==PH_H1Q)
        { s1=&p.W1[(size_t)(n0+nn)*Dd + k0+kk0]; s2=&Wdb[(size_t)(n0+nn)*Dd + k0+kk0]; }
      else if constexpr (PHASE==PH_PRED || PHASE==PH_R)
        { s1=&p.W2[(size_t)(n0+nn)*Hh + k0+kk0]; s2=&Wdb[(size_t)(n0+nn)*Hh + k0+kk0]; }
      else /*PH_OUTC*/
        { s1=&p.Wout[(size_t)(n0+nn)*Dd + k0+kk0]; }
      float4 f0=*(const float4*)s1, f1=*(const float4*)(s1+4);
      if (s2){
        float4 g0=*(const float4*)s2, g1=*(const float4*)(s2+4);
        f0.x+=g0.x; f0.y+=g0.y; f0.z+=g0.z; f0.w+=g0.w;
        f1.x+=g1.x; f1.y+=g1.y; f1.z+=g1.z; f1.w+=g1.w;
      }
      u8v o; o[0]=f2b(f0.x);o[1]=f2b(f0.y);o[2]=f2b(f0.z);o[3]=f2b(f0.w);
             o[4]=f2b(f1.x);o[5]=f2b(f1.y);o[6]=f2b(f1.z);o[7]=f2b(f1.w);
      *(u8v*)&Bs[nn*STR+kk0] = o;
    }
    __syncthreads();
    s8v a  = *(const s8v*)&As[(wm*16 + l16)*STR + quad*8];
    s8v b0 = *(const s8v*)&Bs[(wn*32 +      l16)*STR + quad*8];
    s8v b1 = *(const s8v*)&Bs[(wn*32 + 16 + l16)*STR + quad*8];
    acc0 = __builtin_amdgcn_mfma_f32_16x16x32_bf16(a, b0, acc0, 0,0,0);
    acc1 = __builtin_amdgcn_mfma_f32_16x16x32_bf16(a, b1, acc1, 0,0,0);
    __syncthreads();
  }

  // ---- epilogue: D row = quad*4+r, col = l16 ----
  float al=0.f, lr=0.f, et=0.f;
  if constexpr (PHASE==PH_UPD1 || PHASE==PH_UPD2){
    al = p.gates[nc]; lr = p.gates[NCn+nc]; et = p.gates[2*NCn+nc];
  }
  #pragma unroll
  for (int nf=0; nf<2; nf++){
    const f4v& av = nf ? acc1 : acc0;
    #pragma unroll
    for (int r=0; r<4; r++){
      int m = m0 + wm*16 + quad*4 + r;
      int n = n0 + wn*32 + nf*16 + l16;
      float v = av[r];
      if constexpr (PHASE==PH_H1){
        p.h1[(size_t)m*Hh+n] = f2b(v);
        p.a1[(size_t)m*Hh+n] = f2b(silu_(v));
      }
      else if constexpr (PHASE==PH_H1Q) p.d1b[(size_t)m*Hh+n] = f2b(silu_(v));
      else if constexpr (PHASE==PH_PRED){
        float e = clip1_(v - b2f(p.vbuf[cidx(m,n,nc)]));
        p.d2b[(size_t)m*Dd+n] = f2b(0.03125f*e);
      }
      else if constexpr (PHASE==PH_D1)
        p.d1b[(size_t)m*Hh+n] = f2b(v * dsilu_(b2f(p.h1[(size_t)m*Hh+n])));
      else if constexpr (PHASE==PH_R)    p.rbuf[(size_t)m*Dd+n] = f2b(v);
      else if constexpr (PHASE==PH_OUTC) p.out[cidx(m,n,nc)] = v;
      else if constexpr (PHASE==PH_UPD1){
        size_t idx = (size_t)m*Dd+n;
        float m1 = et*p.M1[idx] - lr*clip1_(v);
        p.M1[idx] = m1;
        Wdnew[idx] = (1.0f-al)*Wdold[idx] + m1;
      }
      else if constexpr (PHASE==PH_UPD2){
        size_t idx = (size_t)m*Hh+n;
        float m2 = et*p.M2[idx] - lr*clip1_(v);
        p.M2[idx] = m2;
        Wdnew[idx] = (1.0f-al)*Wdold[idx] + m2;
      }
    }
  }
}

// ================= persistent cooperative scan kernel ===========================
__global__ __launch_bounds__(256)
void scan_k(Ptrs p){
  cg::grid_group grid = cg::this_grid();
  __shared__ ushort_t As[32*40];
  __shared__ ushort_t Bs[64*40];
  const int bid = blockIdx.x;

  for (int nc=0; nc<NCn; ++nc){
    const float* Wd1r = (nc&1) ? p.Wd1b : p.Wd1a;
    float*       Wd1w = (nc&1) ? p.Wd1a : p.Wd1b;
    const float* Wd2r = (nc&1) ? p.Wd2b : p.Wd2a;
    float*       Wd2w = (nc&1) ? p.Wd2a : p.Wd2b;

    // P1: H1(nc) 256 tiles + OUTC(nc-1) 128 tiles (independent)
    for (int t=bid; t<384; t+=NB){
      if (t<256) do_tile<PH_H1,Dd>(p, nc, t&15, t>>4, Wd1r, nullptr, nullptr, As, Bs);
      else if (nc>0){ int tt=t-256; do_tile<PH_OUTC,Dd>(p, nc-1, tt&15, tt>>4, nullptr,nullptr,nullptr, As, Bs); }
    }
    grid.sync();
    // P2: PRED 128 tiles (M=512,N=512,K=1024)
    for (int t=bid; t<128; t+=NB)
      do_tile<PH_PRED,Hh>(p, nc, t&15, t>>4, Wd2r, nullptr, nullptr, As, Bs);
    grid.sync();
    // P3: D1 256 tiles + UPD2 256 tiles (D1 reads Wd2r; UPD2 writes Wd2w)
    for (int t=bid; t<512; t+=NB){
      if (t<256) do_tile<PH_D1,Dd>(p, nc, t&15, t>>4, Wd2r, nullptr, nullptr, As, Bs);
      else { int tt=t-256; do_tile<PH_UPD2,MROW>(p, nc, tt&15, tt>>4, nullptr, Wd2r, Wd2w, As, Bs); }
    }
    grid.sync();
    // P4: UPD1 256 tiles (M=1024,N=512)
    for (int t=bid; t<256; t+=NB)
      do_tile<PH_UPD1,MROW>(p, nc, t&31, t>>5, nullptr, Wd1r, Wd1w, As, Bs);
    grid.sync();
    // P5: H1Q 256 tiles (uses updated Wd1w)
    for (int t=bid; t<256; t+=NB)
      do_tile<PH_H1Q,Dd>(p, nc, t&15, t>>4, Wd1w, nullptr, nullptr, As, Bs);
    grid.sync();
    // P6: R 128 tiles (uses updated Wd2w)
    for (int t=bid; t<128; t+=NB)
      do_tile<PH_R,Hh>(p, nc, t&15, t>>4, Wd2w, nullptr, nullptr, As, Bs);
    grid.sync();
  }
  // tail: OUTC for last chunk
  for (int t=bid; t<128; t+=NB)
    do_tile<PH_OUTC,Dd>(p, NCn-1, t&15, t>>4, nullptr, nullptr, nullptr, As, Bs);
}

// ================= projection GEMM: 64x64 tile (standalone, big grid) ============
__global__ __launch_bounds__(256)
void gk_proj(Ptrs p){
  constexpr int STR=40;
  __shared__ ushort_t As[64*STR];
  __shared__ ushort_t Bs[64*STR];
  const float* Wp = blockIdx.z==0 ? p.Wk : (blockIdx.z==1 ? p.Wv : p.Wq);
  ushort_t*    Cp = blockIdx.z==0 ? p.kbuf : (blockIdx.z==1 ? p.vbuf : p.qbuf);
  const int tid = threadIdx.x;
  const int m0 = blockIdx.x*64, n0 = blockIdx.y*64;
  const int wave = tid>>6, lane = tid&63;
  const int wm = wave&1, wn = wave>>1;
  const int quad = lane>>4, l16 = lane&15;
  f4v zz = {0.f,0.f,0.f,0.f};
  f4v acc[2][2]; acc[0][0]=zz; acc[0][1]=zz; acc[1][0]=zz; acc[1][1]=zz;

  for (int k0=0; k0<Dd; k0+=32){
    int mm = tid>>2, kk0 = (tid&3)*8;
    {
      const float* s = &p.x[(size_t)(m0+mm)*Dd + k0+kk0];
      float4 f0=*(const float4*)s, f1=*(const float4*)(s+4);
      u8v o; o[0]=f2b(f0.x);o[1]=f2b(f0.y);o[2]=f2b(f0.z);o[3]=f2b(f0.w);
             o[4]=f2b(f1.x);o[5]=f2b(f1.y);o[6]=f2b(f1.z);o[7]=f2b(f1.w);
      *(u8v*)&As[mm*STR+kk0] = o;
    }
    {
      const float* s = &Wp[(size_t)(n0+mm)*Dd + k0+kk0];
      float4 f0=*(const float4*)s, f1=*(const float4*)(s+4);
      u8v o; o[0]=f2b(f0.x);o[1]=f2b(f0.y);o[2]=f2b(f0.z);o[3]=f2b(f0.w);
             o[4]=f2b(f1.x);o[5]=f2b(f1.y);o[6]=f2b(f1.z);o[7]=f2b(f1.w);
      *(u8v*)&Bs[mm*STR+kk0] = o;
    }
    __syncthreads();
    s8v a0 = *(const s8v*)&As[(wm*32 +      l16)*STR + quad*8];
    s8v a1 = *(const s8v*)&As[(wm*32 + 16 + l16)*STR + quad*8];
    s8v b0 = *(const s8v*)&Bs[(wn*32 +      l16)*STR + quad*8];
    s8v b1 = *(const s8v*)&Bs[(wn*32 + 16 + l16)*STR + quad*8];
    acc[0][0] = __builtin_amdgcn_mfma_f32_16x16x32_bf16(a0, b0, acc[0][0], 0,0,0);
    acc[0][1] = __builtin_amdgcn_mfma_f32_16x16x32_bf16(a0, b1, acc[0][1], 0,0,0);
    acc[1][0] = __builtin_amdgcn_mfma_f32_16x16x32_bf16(a1, b0, acc[1][0], 0,0,0);
    acc[1][1] = __builtin_amdgcn_mfma_f32_16x16x32_bf16(a1, b1, acc[1][1], 0,0,0);
    __syncthreads();
  }
  #pragma unroll
  for (int mf=0; mf<2; mf++)
    #pragma unroll
    for (int nf=0; nf<2; nf++)
      #pragma unroll
      for (int r=0; r<4; r++){
        int m = m0 + wm*32 + mf*16 + quad*4 + r;
        int n = n0 + wn*32 + nf*16 + l16;
        Cp[(size_t)m*Dd+n] = f2b(acc[mf][nf][r]);
      }
}

// ---------------- zero the scan state --------------------------------------------
__global__ __launch_bounds__(256)
void zero_k(float* __restrict__ ptr, int n){
  int i = blockIdx.x*256 + threadIdx.x;
  int stride = gridDim.x*256;
  for (; i < n; i += stride) ptr[i] = 0.0f;
}

// ---------------- halo save (last 3 rows of each chunk, pre-conv) ----------------
__global__ void halo_k(const ushort_t* __restrict__ kbuf, const ushort_t* __restrict__ vbuf,
                       const ushort_t* __restrict__ qbuf, ushort_t* __restrict__ halo){
  int bid = blockIdx.x;
  int t = bid / (NCn*Bb);
  int rem = bid % (NCn*Bb);
  int nc = rem / Bb, b = rem % Bb;
  const ushort_t* src = (t==0)?kbuf:((t==1)?vbuf:qbuf);
  ushort_t* dst = halo + (((size_t)t*NCn + nc)*Bb + b)*3*Dd;
  for (int e = threadIdx.x; e < 3*Dd; e += 256){
    int j = e / Dd, d = e % Dd;
    int s = nc*CSc + 61 + j;
    dst[e] = src[((size_t)b*Ss + s)*Dd + d];
  }
}

// ---------------- in-place causal depthwise conv (K=4) ---------------------------
__global__ void conv_k(ushort_t* __restrict__ kbuf, ushort_t* __restrict__ vbuf, ushort_t* __restrict__ qbuf,
                       const float* __restrict__ ckw, const float* __restrict__ ckb,
                       const float* __restrict__ cvw, const float* __restrict__ cvb,
                       const float* __restrict__ cqw, const float* __restrict__ cqb,
                       const ushort_t* __restrict__ halo){
  int bid = blockIdx.x;
  int t = bid / (NCn*Bb);
  int rem = bid % (NCn*Bb);
  int nc = rem / Bb, b = rem % Bb;
  ushort_t* buf = (t==0)?kbuf:((t==1)?vbuf:qbuf);
  const float* cw = (t==0)?ckw:((t==1)?cvw:cqw);
  const float* cb = (t==0)?ckb:((t==1)?cvb:cqb);
  const ushort_t* hl = halo + (((size_t)t*NCn + (nc>0?nc-1:0))*Bb + b)*3*Dd;
  for (int rep=0; rep<2; ++rep){
    int d = threadIdx.x + rep*256;
    float w0 = cw[d*4+0], w1 = cw[d*4+1], w2 = cw[d*4+2], w3 = cw[d*4+3];
    float bias = cb[d];
    float p1, p2, p3;
    if (nc == 0) { p1=p2=p3=0.0f; }
    else { p1 = b2f(hl[2*Dd+d]); p2 = b2f(hl[1*Dd+d]); p3 = b2f(hl[0*Dd+d]); }
    ushort_t* row = buf + ((size_t)b*Ss + nc*CSc)*Dd + d;
    for (int c=0;c<CSc;++c){
      float cur = b2f(row[(size_t)c*Dd]);
      float o = w3*cur + w2*p1 + w1*p2 + w0*p3 + bias;
      p3 = p2; p2 = p1; p1 = cur;
      row[(size_t)c*Dd] = f2b(o);
    }
  }
}

// ---------------- per-chunk scalar gates -----------------------------------------
__global__ __launch_bounds__(256)
void gates_k(const float* __restrict__ x,
             const float* __restrict__ wd, const float* __restrict__ bd,
             const float* __restrict__ wl, const float* __restrict__ bl,
             const float* __restrict__ we, const float* __restrict__ be,
             float* __restrict__ gates){
  int nc = blockIdx.x;
  int wave = threadIdx.x >> 6, lane = threadIdx.x & 63;
  __shared__ float red[4][3];
  float accA=0.f, accL=0.f, accE=0.f;
  float bdv = bd[0], blv = bl[0], bev = be[0];
  for (int pi = wave; pi < Bb*CSc; pi += 4) {
    int b = pi / CSc, c = pi % CSc;
    const float* xr = x + ((size_t)b*Ss + nc*CSc + c)*Dd + lane*8;
    float da=0.f, dl=0.f, de=0.f;
    #pragma unroll
    for (int u=0;u<8;++u){
      float xv = xr[u];
      int d = lane*8+u;
      da += xv*wd[d]; dl += xv*wl[d]; de += xv*we[d];
    }
    #pragma unroll
    for (int off=32; off; off>>=1){
      da += __shfl_down(da, off);
      dl += __shfl_down(dl, off);
      de += __shfl_down(de, off);
    }
    if (lane==0){
      accA += sig_(da + bdv);
      accL += sig_(dl + blv);
      accE += sig_(de + bev);
    }
  }
  if (lane==0){ red[wave][0]=accA; red[wave][1]=accL; red[wave][2]=accE; }
  __syncthreads();
  if (threadIdx.x==0){
    float a=0.f,l=0.f,e=0.f;
    for (int w=0;w<4;w++){ a+=red[w][0]; l+=red[w][1]; e+=red[w][2]; }
    gates[nc]        = a*(1.0f/512.0f);
    gates[NCn+nc]    = l*(1.0f/512.0f);
    gates[2*NCn+nc]  = e*(1.0f/512.0f);
  }
}

extern "C" void kernel_launch(void* const* d_in, const int* in_sizes, int n_in,
                              void* d_out, int out_size, void* d_ws, size_t ws_size,
                              hipStream_t stream) {
  (void)in_sizes; (void)n_in; (void)out_size;
  const float* x       = (const float*)d_in[0];
  const float* Wk      = (const float*)d_in[1];
  const float* Wv      = (const float*)d_in[2];
  const float* Wq      = (const float*)d_in[3];
  const float* Wout    = (const float*)d_in[4];
  const float* ckw     = (const float*)d_in[5];
  const float* ckb     = (const float*)d_in[6];
  const float* cvw     = (const float*)d_in[7];
  const float* cvb     = (const float*)d_in[8];
  const float* cqw     = (const float*)d_in[9];
  const float* cqb     = (const float*)d_in[10];
  const float* w_decay = (const float*)d_in[11];
  const float* b_decay = (const float*)d_in[12];
  const float* w_lr    = (const float*)d_in[13];
  const float* b_lr    = (const float*)d_in[14];
  const float* w_eta   = (const float*)d_in[15];
  const float* b_eta   = (const float*)d_in[16];
  const float* W1      = (const float*)d_in[17];
  const float* W2      = (const float*)d_in[18];

  char* base = (char*)d_ws;
  size_t off = 0;
  auto alloc_f = [&](size_t n)->float*   { float* r=(float*)(base+off);   off += n*4; return r; };
  auto alloc_b = [&](size_t n)->ushort_t*{ ushort_t* r=(ushort_t*)(base+off); off += n*2; off=(off+15)&~15ull; return r; };

  // zero-init group first (contiguous): Wd1a, Wd2a, M1, M2
  float* Wd1a = alloc_f((size_t)Hh*Dd);
  float* Wd2a = alloc_f((size_t)Dd*Hh);
  float* M1   = alloc_f((size_t)Hh*Dd);
  float* M2   = alloc_f((size_t)Dd*Hh);
  float* Wd1b = alloc_f((size_t)Hh*Dd);
  float* Wd2b = alloc_f((size_t)Dd*Hh);
  float* gates= alloc_f(3*NCn + 4);

  const size_t BSD = (size_t)Bb*Ss*Dd;
  ushort_t* kbuf = alloc_b(BSD);
  ushort_t* vbuf = alloc_b(BSD);
  ushort_t* qbuf = alloc_b(BSD);
  ushort_t* halo = alloc_b((size_t)3*NCn*Bb*3*Dd);
  ushort_t* h1   = alloc_b((size_t)MROW*Hh);
  ushort_t* a1   = alloc_b((size_t)MROW*Hh);
  ushort_t* d1b  = alloc_b((size_t)MROW*Hh);
  ushort_t* d2b  = alloc_b((size_t)MROW*Dd);
  ushort_t* rbuf = alloc_b((size_t)MROW*Dd);

  if (ws_size < off) return;  // clean fail instead of fault

  zero_k<<<512, 256, 0, stream>>>(Wd1a, 4*Hh*Dd);

  Ptrs p;
  p.x=x; p.Wk=Wk; p.Wv=Wv; p.Wq=Wq; p.Wout=Wout; p.W1=W1; p.W2=W2;
  p.kbuf=kbuf; p.vbuf=vbuf; p.qbuf=qbuf; p.rbuf=rbuf;
  p.h1=h1; p.a1=a1; p.d1b=d1b; p.d2b=d2b;
  p.Wd1a=Wd1a; p.Wd1b=Wd1b; p.Wd2a=Wd2a; p.Wd2b=Wd2b; p.M1=M1; p.M2=M2;
  p.gates=gates; p.out=(float*)d_out;

  gk_proj<<<dim3(Bb*Ss/64, Dd/64, 3), 256, 0, stream>>>(p);
  halo_k<<<3*NCn*Bb, 256, 0, stream>>>(kbuf, vbuf, qbuf, halo);
  conv_k<<<3*NCn*Bb, 256, 0, stream>>>(kbuf, vbuf, qbuf, ckw, ckb, cvw, cvb, cqw, cqb, halo);
  gates_k<<<NCn, 256, 0, stream>>>(x, w_decay, b_decay, w_lr, b_lr, w_eta, b_eta, gates);

  // whole 64-chunk scan in ONE cooperative launch (6 grid syncs per chunk)
  void* args[] = { (void*)&p };
  hipLaunchCooperativeKernel((void*)scan_k, dim3(NB), dim3(256), args, 0, stream);
}

// Round 5
// 18845.280 us; speedup vs baseline: 1.0590x; 1.0590x over previous
//
#include <hip/hip_runtime.h>

#define Bb 8
#define Ss 4096
#define Dd 512
#define Hh 1024
#define CSc 64
#define NCn 64
#define MROW 512  // Bb*CSc
#define NB 256    // persistent grid blocks

typedef unsigned short ushort_t;
typedef short s8v __attribute__((ext_vector_type(8)));
typedef unsigned short u8v __attribute__((ext_vector_type(8)));
typedef float f4v __attribute__((ext_vector_type(4)));

enum { PH_H1=0, PH_PRED, PH_D1, PH_UPD1, PH_UPD2, PH_H1Q, PH_R, PH_OUTC };

struct Ptrs {
  const float *x, *Wk, *Wv, *Wq, *Wout, *W1, *W2;
  ushort_t *kbuf, *vbuf, *qbuf, *rbuf;
  ushort_t *h1, *a1, *d1b, *d2b;
  ushort_t *e1a, *e1b, *e2a, *e2b, *e2Ta, *e2Tb, *woutb;
  float *Wd1, *Wd2, *M1, *M2;
  float *gates;
  unsigned *bar;
  float *out;
};

__device__ __forceinline__ float b2f(ushort_t u){
  union { unsigned int i; float f; } c; c.i = ((unsigned int)u) << 16; return c.f;
}
__device__ __forceinline__ ushort_t f2b(float f){
  union { float f; unsigned int i; } c; c.f = f;
  unsigned int i = c.i;
  i += 0x7fffu + ((i >> 16) & 1u);   // RTNE
  return (ushort_t)(i >> 16);
}
__device__ __forceinline__ float sig_(float v){ return 1.0f/(1.0f+__expf(-v)); }
__device__ __forceinline__ float silu_(float v){ return v*sig_(v); }
__device__ __forceinline__ float dsilu_(float v){ float s=sig_(v); return s*(1.0f + v*(1.0f-s)); }
__device__ __forceinline__ float clip1_(float v){ return fminf(fmaxf(v,-1.0f),1.0f); }
__device__ __forceinline__ size_t cidx(int m, int d, int nc){
  return ((size_t)((m>>6)*Ss) + nc*CSc + (m&63))*Dd + d;
}

// ---- lean grid barrier: agent-scope generation barrier, thread0 arrives ----
__device__ __forceinline__ void gbar(unsigned* bar){
  __syncthreads();
  if (threadIdx.x==0){
    __threadfence();
    unsigned g = __hip_atomic_load(&bar[1], __ATOMIC_RELAXED, __HIP_MEMORY_SCOPE_AGENT);
    unsigned a = __hip_atomic_fetch_add(&bar[0], 1u, __ATOMIC_ACQ_REL, __HIP_MEMORY_SCOPE_AGENT);
    if (a == NB-1u){
      __hip_atomic_store(&bar[0], 0u, __ATOMIC_RELAXED, __HIP_MEMORY_SCOPE_AGENT);
      __hip_atomic_fetch_add(&bar[1], 1u, __ATOMIC_RELEASE, __HIP_MEMORY_SCOPE_AGENT);
    } else {
      while (__hip_atomic_load(&bar[1], __ATOMIC_ACQUIRE, __HIP_MEMORY_SCOPE_AGENT) == g)
        __builtin_amdgcn_s_sleep(1);
    }
    __threadfence();
  }
  __syncthreads();
}

// ======= one 32x64 tile, 512 threads = 8 waves (2m x 4n), wave = 16x16 =========
template<int PHASE, int KD>
__device__ void do_tile(const Ptrs& p, int nc, int tm, int tn,
                        const ushort_t* Eb, ushort_t* En, ushort_t* EnT,
                        ushort_t* As, ushort_t* Bs)
{
  constexpr int STR = 40;  // shorts; 80B rows, 16B aligned
  const int tid = threadIdx.x;
  const int m0 = tm*32, n0 = tn*64;
  const int wave = tid>>6, lane = tid&63;
  const int wm = wave&1, wn = wave>>1;       // 2 x 4
  const int quad = lane>>4, l16 = lane&15;
  f4v acc = {0.f,0.f,0.f,0.f};

  for (int k0=0; k0<KD; k0+=32){
    if (tid < 128){
      // ---- stage A: 32 m-rows x 32 k ----
      if constexpr (PHASE==PH_UPD1 || PHASE==PH_UPD2){
        int kk = tid&31, mm0 = (tid>>5)*8;
        const ushort_t* src; int str;
        if constexpr (PHASE==PH_UPD1){ src=p.d1b; str=Hh; } else { src=p.d2b; str=Dd; }
        u8v v = *(const u8v*)&src[(size_t)(k0+kk)*str + m0+mm0];
        #pragma unroll
        for (int j=0;j<8;j++) As[(mm0+j)*STR+kk] = v[j];
      } else {
        int mm = tid>>2, kk0 = (tid&3)*8;
        const ushort_t* s;
        if constexpr (PHASE==PH_H1)        s = &p.kbuf[cidx(m0+mm, k0+kk0, nc)];
        else if constexpr (PHASE==PH_H1Q)  s = &p.qbuf[cidx(m0+mm, k0+kk0, nc)];
        else if constexpr (PHASE==PH_PRED) s = &p.a1[(size_t)(m0+mm)*Hh + k0+kk0];
        else if constexpr (PHASE==PH_R)    s = &p.d1b[(size_t)(m0+mm)*Hh + k0+kk0];
        else if constexpr (PHASE==PH_D1)   s = &p.d2b[(size_t)(m0+mm)*Dd + k0+kk0];
        else /*PH_OUTC*/                   s = &p.rbuf[(size_t)(m0+mm)*Dd + k0+kk0];
        *(u8v*)&As[mm*STR+kk0] = *(const u8v*)s;
      }
    } else if (tid < 384){
      // ---- stage B: 64 n-rows x 32 k (Bs[nn][kk] = B[k][n]) ----
      int e = tid-128;
      if constexpr (PHASE==PH_UPD1 || PHASE==PH_UPD2){
        int kk = e&31, nn0 = (e>>5)*8;
        u8v v;
        if constexpr (PHASE==PH_UPD1) v = *(const u8v*)&p.kbuf[cidx(k0+kk, n0+nn0, nc)];
        else                          v = *(const u8v*)&p.a1[(size_t)(k0+kk)*Hh + n0+nn0];
        #pragma unroll
        for (int j=0;j<8;j++) Bs[(nn0+j)*STR+kk] = v[j];
      } else {
        int nn = e>>2, kk0 = (e&3)*8;
        const ushort_t* s;
        if constexpr (PHASE==PH_PRED || PHASE==PH_R) s = &Eb[(size_t)(n0+nn)*Hh + k0+kk0];
        else /*H1,H1Q: e1[h][d]; D1: e2T[h][d]; OUTC: woutb[d][k]*/
                                                     s = &Eb[(size_t)(n0+nn)*Dd + k0+kk0];
        *(u8v*)&Bs[nn*STR+kk0] = *(const u8v*)s;
      }
    }
    __syncthreads();
    s8v a = *(const s8v*)&As[(wm*16 + l16)*STR + quad*8];
    s8v b = *(const s8v*)&Bs[(wn*16 + l16)*STR + quad*8];
    acc = __builtin_amdgcn_mfma_f32_16x16x32_bf16(a, b, acc, 0,0,0);
    __syncthreads();
  }

  // ---- epilogue: D row = quad*4+r, col = l16 ----
  float al=0.f, lr=0.f, et=0.f;
  if constexpr (PHASE==PH_UPD1 || PHASE==PH_UPD2){
    al = p.gates[nc]; lr = p.gates[NCn+nc]; et = p.gates[2*NCn+nc];
  }
  #pragma unroll
  for (int r=0; r<4; r++){
    int m = m0 + wm*16 + quad*4 + r;
    int n = n0 + wn*16 + l16;
    float v = acc[r];
    if constexpr (PHASE==PH_H1){
      p.h1[(size_t)m*Hh+n] = f2b(v);
      p.a1[(size_t)m*Hh+n] = f2b(silu_(v));
    }
    else if constexpr (PHASE==PH_H1Q) p.d1b[(size_t)m*Hh+n] = f2b(silu_(v));
    else if constexpr (PHASE==PH_PRED){
      float e = clip1_(v - b2f(p.vbuf[cidx(m,n,nc)]));
      p.d2b[(size_t)m*Dd+n] = f2b(0.03125f*e);   // scale = 2/CS
    }
    else if constexpr (PHASE==PH_D1)
      p.d1b[(size_t)m*Hh+n] = f2b(v * dsilu_(b2f(p.h1[(size_t)m*Hh+n])));
    else if constexpr (PHASE==PH_R)    p.rbuf[(size_t)m*Dd+n] = f2b(v);
    else if constexpr (PHASE==PH_OUTC) p.out[cidx(m,n,nc)] = v;
    else if constexpr (PHASE==PH_UPD1){
      size_t idx = (size_t)m*Dd+n;     // m=h, n=d
      float m1 = et*p.M1[idx] - lr*clip1_(v);
      p.M1[idx] = m1;
      float wd = (1.0f-al)*p.Wd1[idx] + m1;
      p.Wd1[idx] = wd;
      En[idx] = f2b(p.W1[idx] + wd);
    }
    else if constexpr (PHASE==PH_UPD2){
      size_t idx = (size_t)m*Hh+n;     // m=d, n=h
      float m2 = et*p.M2[idx] - lr*clip1_(v);
      p.M2[idx] = m2;
      float wd = (1.0f-al)*p.Wd2[idx] + m2;
      p.Wd2[idx] = wd;
      float ev = p.W2[idx] + wd;
      En[idx] = f2b(ev);
      EnT[(size_t)n*Dd+m] = f2b(ev);
    }
  }
}

// ================= persistent scan kernel: 5 barriers/chunk =====================
__global__ __launch_bounds__(512)
void scan_k(Ptrs p){
  __shared__ ushort_t As[32*40];
  __shared__ ushort_t Bs[64*40];
  const int bid = blockIdx.x;

  for (int nc=0; nc<NCn; ++nc){
    ushort_t* e1c = (nc&1)?p.e1b:p.e1a;  ushort_t* e1n = (nc&1)?p.e1a:p.e1b;
    ushort_t* e2c = (nc&1)?p.e2b:p.e2a;  ushort_t* e2n = (nc&1)?p.e2a:p.e2b;
    ushort_t* e2Tc= (nc&1)?p.e2Tb:p.e2Ta;ushort_t* e2Tn= (nc&1)?p.e2Ta:p.e2Tb;

    // P1: H1(nc) 256 tiles  ∥  R(nc-1) 128 tiles (e2c = state after nc-1)
    for (int t=bid; t<384; t+=NB){
      if (t<256) do_tile<PH_H1,Dd>(p, nc, t&15, t>>4, e1c, nullptr, nullptr, As, Bs);
      else if (nc>0){ int tt=t-256; do_tile<PH_R,Hh>(p, nc-1, tt&15, tt>>4, e2c, nullptr, nullptr, As, Bs); }
    }
    gbar(p.bar);
    // P2: PRED(nc) 128  ∥  OUTC(nc-1) 128
    for (int t=bid; t<256; t+=NB){
      if (t<128) do_tile<PH_PRED,Hh>(p, nc, t&15, t>>4, e2c, nullptr, nullptr, As, Bs);
      else if (nc>0){ int tt=t-128; do_tile<PH_OUTC,Dd>(p, nc-1, tt&15, tt>>4, p.woutb, nullptr, nullptr, As, Bs); }
    }
    gbar(p.bar);
    // P3: D1(nc) 256 (reads e2Tc)  ∥  UPD2(nc) 256 (writes e2n/e2Tn)
    for (int t=bid; t<512; t+=NB){
      if (t<256) do_tile<PH_D1,Dd>(p, nc, t&15, t>>4, e2Tc, nullptr, nullptr, As, Bs);
      else { int tt=t-256; do_tile<PH_UPD2,MROW>(p, nc, tt&15, tt>>4, nullptr, e2n, e2Tn, As, Bs); }
    }
    gbar(p.bar);
    // P4: UPD1(nc) 256 (writes e1n)
    for (int t=bid; t<256; t+=NB)
      do_tile<PH_UPD1,MROW>(p, nc, t&31, t>>5, nullptr, e1n, nullptr, As, Bs);
    gbar(p.bar);
    // P5: H1Q(nc) 256 (reads e1n)
    for (int t=bid; t<256; t+=NB)
      do_tile<PH_H1Q,Dd>(p, nc, t&15, t>>4, e1n, nullptr, nullptr, As, Bs);
    gbar(p.bar);
  }
  // tail: R(63) then OUTC(63)
  ushort_t* e2fin = (NCn&1)?p.e2b:p.e2a;   // state after chunk 63
  for (int t=bid; t<128; t+=NB)
    do_tile<PH_R,Hh>(p, NCn-1, t&15, t>>4, e2fin, nullptr, nullptr, As, Bs);
  gbar(p.bar);
  for (int t=bid; t<128; t+=NB)
    do_tile<PH_OUTC,Dd>(p, NCn-1, t&15, t>>4, p.woutb, nullptr, nullptr, As, Bs);
}

// ================= projection GEMM: 64x64 tile (standalone, big grid) ============
__global__ __launch_bounds__(256)
void gk_proj(Ptrs p){
  constexpr int STR=40;
  __shared__ ushort_t As[64*STR];
  __shared__ ushort_t Bs[64*STR];
  const float* Wp = blockIdx.z==0 ? p.Wk : (blockIdx.z==1 ? p.Wv : p.Wq);
  ushort_t*    Cp = blockIdx.z==0 ? p.kbuf : (blockIdx.z==1 ? p.vbuf : p.qbuf);
  const int tid = threadIdx.x;
  const int m0 = blockIdx.x*64, n0 = blockIdx.y*64;
  const int wave = tid>>6, lane = tid&63;
  const int wm = wave&1, wn = wave>>1;
  const int quad = lane>>4, l16 = lane&15;
  f4v zz = {0.f,0.f,0.f,0.f};
  f4v acc[2][2]; acc[0][0]=zz; acc[0][1]=zz; acc[1][0]=zz; acc[1][1]=zz;

  for (int k0=0; k0<Dd; k0+=32){
    int mm = tid>>2, kk0 = (tid&3)*8;
    {
      const float* s = &p.x[(size_t)(m0+mm)*Dd + k0+kk0];
      float4 f0=*(const float4*)s, f1=*(const float4*)(s+4);
      u8v o; o[0]=f2b(f0.x);o[1]=f2b(f0.y);o[2]=f2b(f0.z);o[3]=f2b(f0.w);
             o[4]=f2b(f1.x);o[5]=f2b(f1.y);o[6]=f2b(f1.z);o[7]=f2b(f1.w);
      *(u8v*)&As[mm*STR+kk0] = o;
    }
    {
      const float* s = &Wp[(size_t)(n0+mm)*Dd + k0+kk0];
      float4 f0=*(const float4*)s, f1=*(const float4*)(s+4);
      u8v o; o[0]=f2b(f0.x);o[1]=f2b(f0.y);o[2]=f2b(f0.z);o[3]=f2b(f0.w);
             o[4]=f2b(f1.x);o[5]=f2b(f1.y);o[6]=f2b(f1.z);o[7]=f2b(f1.w);
      *(u8v*)&Bs[mm*STR+kk0] = o;
    }
    __syncthreads();
    s8v a0 = *(const s8v*)&As[(wm*32 +      l16)*STR + quad*8];
    s8v a1 = *(const s8v*)&As[(wm*32 + 16 + l16)*STR + quad*8];
    s8v b0 = *(const s8v*)&Bs[(wn*32 +      l16)*STR + quad*8];
    s8v b1 = *(const s8v*)&Bs[(wn*32 + 16 + l16)*STR + quad*8];
    acc[0][0] = __builtin_amdgcn_mfma_f32_16x16x32_bf16(a0, b0, acc[0][0], 0,0,0);
    acc[0][1] = __builtin_amdgcn_mfma_f32_16x16x32_bf16(a0, b1, acc[0][1], 0,0,0);
    acc[1][0] = __builtin_amdgcn_mfma_f32_16x16x32_bf16(a1, b0, acc[1][0], 0,0,0);
    acc[1][1] = __builtin_amdgcn_mfma_f32_16x16x32_bf16(a1, b1, acc[1][1], 0,0,0);
    __syncthreads();
  }
  #pragma unroll
  for (int mf=0; mf<2; mf++)
    #pragma unroll
    for (int nf=0; nf<2; nf++)
      #pragma unroll
      for (int r=0; r<4; r++){
        int m = m0 + wm*32 + mf*16 + quad*4 + r;
        int n = n0 + wn*32 + nf*16 + l16;
        Cp[(size_t)m*Dd+n] = f2b(acc[mf][nf][r]);
      }
}

// ---------------- init: zero state + bf16 snapshots of W1/W2/Wout + barrier ------
__global__ __launch_bounds__(256)
void init_k(Ptrs p){
  size_t i = (size_t)blockIdx.x*256 + threadIdx.x;
  size_t stride = (size_t)gridDim.x*256;
  for (size_t j=i; j<(size_t)Hh*Dd; j+=stride){
    p.Wd1[j]=0.f; p.M1[j]=0.f; p.Wd2[j]=0.f; p.M2[j]=0.f;
    p.e1a[j] = f2b(p.W1[j]);
    p.e2a[j] = f2b(p.W2[j]);
    p.e2Ta[j] = f2b(p.W2[(size_t)(j & (Dd-1))*Hh + (j>>9)]);  // [h][d] = W2[d][h]
  }
  for (size_t j=i; j<(size_t)Dd*Dd; j+=stride) p.woutb[j] = f2b(p.Wout[j]);
  if (i < 16) p.bar[i] = 0u;
}

// ---------------- halo save (last 3 rows of each chunk, pre-conv) ----------------
__global__ void halo_k(const ushort_t* __restrict__ kbuf, const ushort_t* __restrict__ vbuf,
                       const ushort_t* __restrict__ qbuf, ushort_t* __restrict__ halo){
  int bid = blockIdx.x;
  int t = bid / (NCn*Bb);
  int rem = bid % (NCn*Bb);
  int nc = rem / Bb, b = rem % Bb;
  const ushort_t* src = (t==0)?kbuf:((t==1)?vbuf:qbuf);
  ushort_t* dst = halo + (((size_t)t*NCn + nc)*Bb + b)*3*Dd;
  for (int e = threadIdx.x; e < 3*Dd; e += 256){
    int j = e / Dd, d = e % Dd;
    int s = nc*CSc + 61 + j;
    dst[e] = src[((size_t)b*Ss + s)*Dd + d];
  }
}

// ---------------- in-place causal depthwise conv (K=4) ---------------------------
__global__ void conv_k(ushort_t* __restrict__ kbuf, ushort_t* __restrict__ vbuf, ushort_t* __restrict__ qbuf,
                       const float* __restrict__ ckw, const float* __restrict__ ckb,
                       const float* __restrict__ cvw, const float* __restrict__ cvb,
                       const float* __restrict__ cqw, const float* __restrict__ cqb,
                       const ushort_t* __restrict__ halo){
  int bid = blockIdx.x;
  int t = bid / (NCn*Bb);
  int rem = bid % (NCn*Bb);
  int nc = rem / Bb, b = rem % Bb;
  ushort_t* buf = (t==0)?kbuf:((t==1)?vbuf:qbuf);
  const float* cw = (t==0)?ckw:((t==1)?cvw:cqw);
  const float* cb = (t==0)?ckb:((t==1)?cvb:cqb);
  const ushort_t* hl = halo + (((size_t)t*NCn + (nc>0?nc-1:0))*Bb + b)*3*Dd;
  for (int rep=0; rep<2; ++rep){
    int d = threadIdx.x + rep*256;
    float w0 = cw[d*4+0], w1 = cw[d*4+1], w2 = cw[d*4+2], w3 = cw[d*4+3];
    float bias = cb[d];
    float p1, p2, p3;
    if (nc == 0) { p1=p2=p3=0.0f; }
    else { p1 = b2f(hl[2*Dd+d]); p2 = b2f(hl[1*Dd+d]); p3 = b2f(hl[0*Dd+d]); }
    ushort_t* row = buf + ((size_t)b*Ss + nc*CSc)*Dd + d;
    for (int c=0;c<CSc;++c){
      float cur = b2f(row[(size_t)c*Dd]);
      float o = w3*cur + w2*p1 + w1*p2 + w0*p3 + bias;
      p3 = p2; p2 = p1; p1 = cur;
      row[(size_t)c*Dd] = f2b(o);
    }
  }
}

// ---------------- per-chunk scalar gates -----------------------------------------
__global__ __launch_bounds__(256)
void gates_k(const float* __restrict__ x,
             const float* __restrict__ wd, const float* __restrict__ bd,
             const float* __restrict__ wl, const float* __restrict__ bl,
             const float* __restrict__ we, const float* __restrict__ be,
             float* __restrict__ gates){
  int nc = blockIdx.x;
  int wave = threadIdx.x >> 6, lane = threadIdx.x & 63;
  __shared__ float red[4][3];
  float accA=0.f, accL=0.f, accE=0.f;
  float bdv = bd[0], blv = bl[0], bev = be[0];
  for (int pi = wave; pi < Bb*CSc; pi += 4) {
    int b = pi / CSc, c = pi % CSc;
    const float* xr = x + ((size_t)b*Ss + nc*CSc + c)*Dd + lane*8;
    float da=0.f, dl=0.f, de=0.f;
    #pragma unroll
    for (int u=0;u<8;++u){
      float xv = xr[u];
      int d = lane*8+u;
      da += xv*wd[d]; dl += xv*wl[d]; de += xv*we[d];
    }
    #pragma unroll
    for (int off=32; off; off>>=1){
      da += __shfl_down(da, off);
      dl += __shfl_down(dl, off);
      de += __shfl_down(de, off);
    }
    if (lane==0){
      accA += sig_(da + bdv);
      accL += sig_(dl + blv);
      accE += sig_(de + bev);
    }
  }
  if (lane==0){ red[wave][0]=accA; red[wave][1]=accL; red[wave][2]=accE; }
  __syncthreads();
  if (threadIdx.x==0){
    float a=0.f,l=0.f,e=0.f;
    for (int w=0;w<4;w++){ a+=red[w][0]; l+=red[w][1]; e+=red[w][2]; }
    gates[nc]        = a*(1.0f/512.0f);
    gates[NCn+nc]    = l*(1.0f/512.0f);
    gates[2*NCn+nc]  = e*(1.0f/512.0f);
  }
}

extern "C" void kernel_launch(void* const* d_in, const int* in_sizes, int n_in,
                              void* d_out, int out_size, void* d_ws, size_t ws_size,
                              hipStream_t stream) {
  (void)in_sizes; (void)n_in; (void)out_size;
  const float* x       = (const float*)d_in[0];
  const float* Wk      = (const float*)d_in[1];
  const float* Wv      = (const float*)d_in[2];
  const float* Wq      = (const float*)d_in[3];
  const float* Wout    = (const float*)d_in[4];
  const float* ckw     = (const float*)d_in[5];
  const float* ckb     = (const float*)d_in[6];
  const float* cvw     = (const float*)d_in[7];
  const float* cvb     = (const float*)d_in[8];
  const float* cqw     = (const float*)d_in[9];
  const float* cqb     = (const float*)d_in[10];
  const float* w_decay = (const float*)d_in[11];
  const float* b_decay = (const float*)d_in[12];
  const float* w_lr    = (const float*)d_in[13];
  const float* b_lr    = (const float*)d_in[14];
  const float* w_eta   = (const float*)d_in[15];
  const float* b_eta   = (const float*)d_in[16];
  const float* W1      = (const float*)d_in[17];
  const float* W2      = (const float*)d_in[18];

  char* base = (char*)d_ws;
  size_t off = 0;
  auto alloc_f = [&](size_t n)->float*   { float* r=(float*)(base+off);   off += n*4; return r; };
  auto alloc_u = [&](size_t n)->unsigned*{ unsigned* r=(unsigned*)(base+off); off += n*4; return r; };
  auto alloc_b = [&](size_t n)->ushort_t*{ ushort_t* r=(ushort_t*)(base+off); off += n*2; off=(off+15)&~15ull; return r; };

  float* Wd1  = alloc_f((size_t)Hh*Dd);
  float* Wd2  = alloc_f((size_t)Dd*Hh);
  float* M1   = alloc_f((size_t)Hh*Dd);
  float* M2   = alloc_f((size_t)Dd*Hh);
  float* gates= alloc_f(3*NCn + 4);
  unsigned* bar = alloc_u(64);

  const size_t BSD = (size_t)Bb*Ss*Dd;
  ushort_t* kbuf = alloc_b(BSD);
  ushort_t* vbuf = alloc_b(BSD);
  ushort_t* qbuf = alloc_b(BSD);
  ushort_t* halo = alloc_b((size_t)3*NCn*Bb*3*Dd);
  ushort_t* h1   = alloc_b((size_t)MROW*Hh);
  ushort_t* a1   = alloc_b((size_t)MROW*Hh);
  ushort_t* d1b  = alloc_b((size_t)MROW*Hh);
  ushort_t* d2b  = alloc_b((size_t)MROW*Dd);
  ushort_t* rbuf = alloc_b((size_t)MROW*Dd);
  ushort_t* e1a  = alloc_b((size_t)Hh*Dd);
  ushort_t* e1b  = alloc_b((size_t)Hh*Dd);
  ushort_t* e2a  = alloc_b((size_t)Dd*Hh);
  ushort_t* e2b  = alloc_b((size_t)Dd*Hh);
  ushort_t* e2Ta = alloc_b((size_t)Hh*Dd);
  ushort_t* e2Tb = alloc_b((size_t)Hh*Dd);
  ushort_t* woutb= alloc_b((size_t)Dd*Dd);

  if (ws_size < off) return;  // clean fail instead of fault

  Ptrs p;
  p.x=x; p.Wk=Wk; p.Wv=Wv; p.Wq=Wq; p.Wout=Wout; p.W1=W1; p.W2=W2;
  p.kbuf=kbuf; p.vbuf=vbuf; p.qbuf=qbuf; p.rbuf=rbuf;
  p.h1=h1; p.a1=a1; p.d1b=d1b; p.d2b=d2b;
  p.e1a=e1a; p.e1b=e1b; p.e2a=e2a; p.e2b=e2b; p.e2Ta=e2Ta; p.e2Tb=e2Tb; p.woutb=woutb;
  p.Wd1=Wd1; p.Wd2=Wd2; p.M1=M1; p.M2=M2;
  p.gates=gates; p.bar=bar; p.out=(float*)d_out;

  init_k<<<1024, 256, 0, stream>>>(p);
  gk_proj<<<dim3(Bb*Ss/64, Dd/64, 3), 256, 0, stream>>>(p);
  halo_k<<<3*NCn*Bb, 256, 0, stream>>>(kbuf, vbuf, qbuf, halo);
  conv_k<<<3*NCn*Bb, 256, 0, stream>>>(kbuf, vbuf, qbuf, ckw, ckb, cvw, cvb, cqw, cqb, halo);
  gates_k<<<NCn, 256, 0, stream>>>(x, w_decay, b_decay, w_lr, b_lr, w_eta, b_eta, gates);

  // whole 64-chunk scan: one cooperative launch, custom agent-scope barriers
  void* args[] = { (void*)&p };
  hipLaunchCooperativeKernel((void*)scan_k, dim3(NB), dim3(512), args, 0, stream);
}

// Round 6
// 10375.948 us; speedup vs baseline: 1.9234x; 1.8162x over previous
//
#include <hip/hip_runtime.h>

#define Bb 8
#define Ss 4096
#define Dd 512
#define Hh 1024
#define CSc 64
#define NCn 64
#define MROW 512  // Bb*CSc
#define NB 256    // persistent grid blocks

typedef unsigned short ushort_t;
typedef short s8v __attribute__((ext_vector_type(8)));
typedef unsigned short u8v __attribute__((ext_vector_type(8)));
typedef float f4v __attribute__((ext_vector_type(4)));

enum { PH_H1=0, PH_PRED, PH_D1, PH_UPD1, PH_UPD2, PH_H1Q, PH_R, PH_OUTC };

struct Ptrs {
  const float *x, *Wk, *Wv, *Wq, *Wout, *W1, *W2;
  ushort_t *kbuf, *vbuf, *qbuf, *rbuf;
  ushort_t *h1, *a1, *d1b, *d2b;
  ushort_t *e1a, *e1b, *e2a, *e2b, *e2Ta, *e2Tb, *woutb;
  float *Wd1, *Wd2, *M1, *M2;
  float *gates;
  unsigned *bar;
  float *out;
};

__device__ __forceinline__ float b2f(ushort_t u){
  union { unsigned int i; float f; } c; c.i = ((unsigned int)u) << 16; return c.f;
}
__device__ __forceinline__ ushort_t f2b(float f){
  union { float f; unsigned int i; } c; c.f = f;
  unsigned int i = c.i;
  i += 0x7fffu + ((i >> 16) & 1u);   // RTNE
  return (ushort_t)(i >> 16);
}
__device__ __forceinline__ float sig_(float v){ return 1.0f/(1.0f+__expf(-v)); }
__device__ __forceinline__ float silu_(float v){ return v*sig_(v); }
__device__ __forceinline__ float dsilu_(float v){ float s=sig_(v); return s*(1.0f + v*(1.0f-s)); }
__device__ __forceinline__ float clip1_(float v){ return fminf(fmaxf(v,-1.0f),1.0f); }
__device__ __forceinline__ size_t cidx(int m, int d, int nc){
  return ((size_t)((m>>6)*Ss) + nc*CSc + (m&63))*Dd + d;
}

// ---- lean grid barrier: relaxed spin + single acquire at exit ----
__device__ __forceinline__ void gbar(unsigned* bar){
  __syncthreads();
  if (threadIdx.x==0){
    unsigned g = __hip_atomic_load(&bar[1], __ATOMIC_RELAXED, __HIP_MEMORY_SCOPE_AGENT);
    unsigned a = __hip_atomic_fetch_add(&bar[0], 1u, __ATOMIC_ACQ_REL, __HIP_MEMORY_SCOPE_AGENT);
    if (a == NB-1u){
      __hip_atomic_store(&bar[0], 0u, __ATOMIC_RELAXED, __HIP_MEMORY_SCOPE_AGENT);
      __hip_atomic_store(&bar[1], g+1u, __ATOMIC_RELEASE, __HIP_MEMORY_SCOPE_AGENT);
    } else {
      while (__hip_atomic_load(&bar[1], __ATOMIC_RELAXED, __HIP_MEMORY_SCOPE_AGENT) == g)
        __builtin_amdgcn_s_sleep(8);
      (void)__hip_atomic_load(&bar[1], __ATOMIC_ACQUIRE, __HIP_MEMORY_SCOPE_AGENT);
    }
  }
  __syncthreads();
}

// ======= one 32x64 tile, 512 thr = 8 waves (2m x 4n), BK=256, LDS double-buf ====
// LDS row stride 264 shorts (528B, 16B-aligned)
#define STRL 264
#define ABUF (32*STRL)
#define BBUF (64*STRL)

template<int PHASE>
__device__ void do_tile(const Ptrs& p, int nc, int tm, int tn, const ushort_t* Eb,
                        ushort_t* En, ushort_t* EnT, ushort_t* As, ushort_t* Bs)
{
  constexpr int KD = (PHASE==PH_PRED||PHASE==PH_R) ? Hh : 512;
  constexpr int NS = KD/256;
  constexpr bool UPD = (PHASE==PH_UPD1 || PHASE==PH_UPD2);
  const int tid = threadIdx.x;
  const int m0 = tm*32, n0 = tn*64;
  const int wave = tid>>6, lane = tid&63;
  const int wm = wave&1, wn = wave>>1;       // 2 x 4
  const int quad = lane>>4, l16 = lane&15;
  f4v acc = {0.f,0.f,0.f,0.f};
  u8v ra[2], rb[4];

  auto loadA = [&](int s){
    int k0 = s*256;
    if constexpr (UPD){
      const ushort_t* src; int str;
      if constexpr (PHASE==PH_UPD1){ src=p.d1b; str=Hh; } else { src=p.d2b; str=Dd; }
      int kk = tid>>1, mm0 = (tid&1)*16;
      const ushort_t* sp = &src[(size_t)(k0+kk)*str + m0+mm0];
      ra[0] = *(const u8v*)sp; ra[1] = *(const u8v*)(sp+8);
    } else {
      int mm = tid>>4, kk0 = (tid&15)*16;
      int m = m0+mm, k = k0+kk0;
      const ushort_t* sp;
      if constexpr (PHASE==PH_H1)        sp = &p.kbuf[cidx(m,k,nc)];
      else if constexpr (PHASE==PH_H1Q)  sp = &p.qbuf[cidx(m,k,nc)];
      else if constexpr (PHASE==PH_PRED) sp = &p.a1[(size_t)m*Hh + k];
      else if constexpr (PHASE==PH_R)    sp = &p.d1b[(size_t)m*Hh + k];
      else if constexpr (PHASE==PH_D1)   sp = &p.d2b[(size_t)m*Dd + k];
      else /*PH_OUTC*/                   sp = &p.rbuf[(size_t)m*Dd + k];
      ra[0] = *(const u8v*)sp; ra[1] = *(const u8v*)(sp+8);
    }
  };
  auto loadB = [&](int s){
    int k0 = s*256;
    if constexpr (UPD){
      int kk = tid>>1, nn0 = (tid&1)*32;
      const ushort_t* sp;
      if constexpr (PHASE==PH_UPD1) sp = &p.kbuf[cidx(k0+kk, n0+nn0, nc)];
      else                          sp = &p.a1[(size_t)(k0+kk)*Hh + n0+nn0];
      rb[0]=*(const u8v*)sp; rb[1]=*(const u8v*)(sp+8);
      rb[2]=*(const u8v*)(sp+16); rb[3]=*(const u8v*)(sp+24);
    } else {
      constexpr int bstr = (PHASE==PH_PRED||PHASE==PH_R) ? Hh : Dd;
      int nn = tid>>3, kk0 = (tid&7)*32;
      const ushort_t* sp = &Eb[(size_t)(n0+nn)*bstr + k0+kk0];
      rb[0]=*(const u8v*)sp; rb[1]=*(const u8v*)(sp+8);
      rb[2]=*(const u8v*)(sp+16); rb[3]=*(const u8v*)(sp+24);
    }
  };
  auto writeAB = [&](int buf){
    ushort_t* da = As + buf*ABUF;
    ushort_t* db = Bs + buf*BBUF;
    if constexpr (UPD){
      int kk = tid>>1, mm0 = (tid&1)*16, nn0 = (tid&1)*32;
      #pragma unroll
      for (int j=0;j<8;j++){
        da[(mm0+j)*STRL+kk]   = ra[0][j];
        da[(mm0+8+j)*STRL+kk] = ra[1][j];
        db[(nn0+j)*STRL+kk]    = rb[0][j];
        db[(nn0+8+j)*STRL+kk]  = rb[1][j];
        db[(nn0+16+j)*STRL+kk] = rb[2][j];
        db[(nn0+24+j)*STRL+kk] = rb[3][j];
      }
    } else {
      int mm = tid>>4, kk0 = (tid&15)*16;
      *(u8v*)&da[mm*STRL+kk0]   = ra[0];
      *(u8v*)&da[mm*STRL+kk0+8] = ra[1];
      int nn = tid>>3, kb0 = (tid&7)*32;
      *(u8v*)&db[nn*STRL+kb0]    = rb[0];
      *(u8v*)&db[nn*STRL+kb0+8]  = rb[1];
      *(u8v*)&db[nn*STRL+kb0+16] = rb[2];
      *(u8v*)&db[nn*STRL+kb0+24] = rb[3];
    }
  };

  loadA(0); loadB(0);
  writeAB(0);
  __syncthreads();
  #pragma unroll
  for (int s=0; s<NS; ++s){
    if (s+1 < NS){ loadA(s+1); loadB(s+1); }
    {
      const ushort_t* ab = As + (s&1)*ABUF + (wm*16+l16)*STRL + quad*8;
      const ushort_t* bb = Bs + (s&1)*BBUF + (wn*16+l16)*STRL + quad*8;
      #pragma unroll
      for (int kk=0; kk<8; ++kk){
        s8v a = *(const s8v*)(ab + kk*32);
        s8v b = *(const s8v*)(bb + kk*32);
        acc = __builtin_amdgcn_mfma_f32_16x16x32_bf16(a, b, acc, 0,0,0);
      }
    }
    if (s+1 < NS){ writeAB((s+1)&1); __syncthreads(); }
  }

  // ---- epilogue: D row = quad*4+r, col = l16 ----
  float al=0.f, lr=0.f, et=0.f;
  if constexpr (UPD){
    al = p.gates[nc]; lr = p.gates[NCn+nc]; et = p.gates[2*NCn+nc];
  }
  #pragma unroll
  for (int r=0; r<4; r++){
    int m = m0 + wm*16 + quad*4 + r;
    int n = n0 + wn*16 + l16;
    float v = acc[r];
    if constexpr (PHASE==PH_H1){
      p.h1[(size_t)m*Hh+n] = f2b(v);
      p.a1[(size_t)m*Hh+n] = f2b(silu_(v));
    }
    else if constexpr (PHASE==PH_H1Q) p.d1b[(size_t)m*Hh+n] = f2b(silu_(v));
    else if constexpr (PHASE==PH_PRED){
      float e = clip1_(v - b2f(p.vbuf[cidx(m,n,nc)]));
      p.d2b[(size_t)m*Dd+n] = f2b(0.03125f*e);   // scale = 2/CS
    }
    else if constexpr (PHASE==PH_D1)
      p.d1b[(size_t)m*Hh+n] = f2b(v * dsilu_(b2f(p.h1[(size_t)m*Hh+n])));
    else if constexpr (PHASE==PH_R)    p.rbuf[(size_t)m*Dd+n] = f2b(v);
    else if constexpr (PHASE==PH_OUTC) p.out[cidx(m,n,nc)] = v;
    else if constexpr (PHASE==PH_UPD1){
      size_t idx = (size_t)m*Dd+n;     // m=h, n=d
      float m1 = et*p.M1[idx] - lr*clip1_(v);
      p.M1[idx] = m1;
      float wd = (1.0f-al)*p.Wd1[idx] + m1;
      p.Wd1[idx] = wd;
      En[idx] = f2b(p.W1[idx] + wd);
    }
    else if constexpr (PHASE==PH_UPD2){
      size_t idx = (size_t)m*Hh+n;     // m=d, n=h
      float m2 = et*p.M2[idx] - lr*clip1_(v);
      p.M2[idx] = m2;
      float wd = (1.0f-al)*p.Wd2[idx] + m2;
      p.Wd2[idx] = wd;
      float ev = p.W2[idx] + wd;
      En[idx] = f2b(ev);
      EnT[(size_t)n*Dd+m] = f2b(ev);
    }
  }
}

// ================= persistent scan kernel: 5 barriers/chunk =====================
__global__ __launch_bounds__(512)
void scan_k(Ptrs p){
  __shared__ ushort_t As[2*ABUF];
  __shared__ ushort_t Bs[2*BBUF];
  const int bid = blockIdx.x;

  for (int nc=0; nc<NCn; ++nc){
    ushort_t* e1c = (nc&1)?p.e1b:p.e1a;  ushort_t* e1n = (nc&1)?p.e1a:p.e1b;
    ushort_t* e2c = (nc&1)?p.e2b:p.e2a;  ushort_t* e2n = (nc&1)?p.e2a:p.e2b;
    ushort_t* e2Tc= (nc&1)?p.e2Tb:p.e2Ta;ushort_t* e2Tn= (nc&1)?p.e2Ta:p.e2Tb;

    // P1 (balanced): blocks 0-127: R(nc-1) [KD=1024]; blocks 128-255: 2x H1(nc)
    if (bid < 128){
      if (nc>0) do_tile<PH_R>(p, nc-1, bid&15, bid>>4, e2c, nullptr, nullptr, As, Bs);
    } else {
      int t = bid-128;
      do_tile<PH_H1>(p, nc, t&15, t>>4, e1c, nullptr, nullptr, As, Bs);
      t += 128;
      do_tile<PH_H1>(p, nc, t&15, t>>4, e1c, nullptr, nullptr, As, Bs);
    }
    gbar(p.bar);
    // P2: PRED(nc) 128 [KD=1024]  |  OUTC(nc-1) 128
    if (bid < 128) do_tile<PH_PRED>(p, nc, bid&15, bid>>4, e2c, nullptr, nullptr, As, Bs);
    else if (nc>0){ int t=bid-128; do_tile<PH_OUTC>(p, nc-1, t&15, t>>4, p.woutb, nullptr, nullptr, As, Bs); }
    gbar(p.bar);
    // P3: D1(nc) 256 (reads e2Tc)  |  UPD2(nc) 256 (writes e2n/e2Tn) — 2 tiles/block
    for (int t=bid; t<512; t+=NB){
      if (t<256) do_tile<PH_D1>(p, nc, t&15, t>>4, e2Tc, nullptr, nullptr, As, Bs);
      else { int tt=t-256; do_tile<PH_UPD2>(p, nc, tt&15, tt>>4, nullptr, e2n, e2Tn, As, Bs); }
    }
    gbar(p.bar);
    // P4: UPD1(nc) 256 (writes e1n)
    do_tile<PH_UPD1>(p, nc, bid&31, bid>>5, nullptr, e1n, nullptr, As, Bs);
    gbar(p.bar);
    // P5: H1Q(nc) 256 (reads e1n)
    do_tile<PH_H1Q>(p, nc, bid&15, bid>>4, e1n, nullptr, nullptr, As, Bs);
    gbar(p.bar);
  }
  // tail: R(63) then OUTC(63)
  ushort_t* e2fin = (NCn&1)?p.e2b:p.e2a;
  if (bid < 128)
    do_tile<PH_R>(p, NCn-1, bid&15, bid>>4, e2fin, nullptr, nullptr, As, Bs);
  gbar(p.bar);
  if (bid < 128)
    do_tile<PH_OUTC>(p, NCn-1, bid&15, bid>>4, p.woutb, nullptr, nullptr, As, Bs);
}

// ================= projection GEMM: 64x64 tile (standalone, big grid) ============
__global__ __launch_bounds__(256)
void gk_proj(Ptrs p){
  constexpr int STR=40;
  __shared__ ushort_t As[64*STR];
  __shared__ ushort_t Bs[64*STR];
  const float* Wp = blockIdx.z==0 ? p.Wk : (blockIdx.z==1 ? p.Wv : p.Wq);
  ushort_t*    Cp = blockIdx.z==0 ? p.kbuf : (blockIdx.z==1 ? p.vbuf : p.qbuf);
  const int tid = threadIdx.x;
  const int m0 = blockIdx.x*64, n0 = blockIdx.y*64;
  const int wave = tid>>6, lane = tid&63;
  const int wm = wave&1, wn = wave>>1;
  const int quad = lane>>4, l16 = lane&15;
  f4v zz = {0.f,0.f,0.f,0.f};
  f4v acc[2][2]; acc[0][0]=zz; acc[0][1]=zz; acc[1][0]=zz; acc[1][1]=zz;

  for (int k0=0; k0<Dd; k0+=32){
    int mm = tid>>2, kk0 = (tid&3)*8;
    {
      const float* s = &p.x[(size_t)(m0+mm)*Dd + k0+kk0];
      float4 f0=*(const float4*)s, f1=*(const float4*)(s+4);
      u8v o; o[0]=f2b(f0.x);o[1]=f2b(f0.y);o[2]=f2b(f0.z);o[3]=f2b(f0.w);
             o[4]=f2b(f1.x);o[5]=f2b(f1.y);o[6]=f2b(f1.z);o[7]=f2b(f1.w);
      *(u8v*)&As[mm*STR+kk0] = o;
    }
    {
      const float* s = &Wp[(size_t)(n0+mm)*Dd + k0+kk0];
      float4 f0=*(const float4*)s, f1=*(const float4*)(s+4);
      u8v o; o[0]=f2b(f0.x);o[1]=f2b(f0.y);o[2]=f2b(f0.z);o[3]=f2b(f0.w);
             o[4]=f2b(f1.x);o[5]=f2b(f1.y);o[6]=f2b(f1.z);o[7]=f2b(f1.w);
      *(u8v*)&Bs[mm*STR+kk0] = o;
    }
    __syncthreads();
    s8v a0 = *(const s8v*)&As[(wm*32 +      l16)*STR + quad*8];
    s8v a1 = *(const s8v*)&As[(wm*32 + 16 + l16)*STR + quad*8];
    s8v b0 = *(const s8v*)&Bs[(wn*32 +      l16)*STR + quad*8];
    s8v b1 = *(const s8v*)&Bs[(wn*32 + 16 + l16)*STR + quad*8];
    acc[0][0] = __builtin_amdgcn_mfma_f32_16x16x32_bf16(a0, b0, acc[0][0], 0,0,0);
    acc[0][1] = __builtin_amdgcn_mfma_f32_16x16x32_bf16(a0, b1, acc[0][1], 0,0,0);
    acc[1][0] = __builtin_amdgcn_mfma_f32_16x16x32_bf16(a1, b0, acc[1][0], 0,0,0);
    acc[1][1] = __builtin_amdgcn_mfma_f32_16x16x32_bf16(a1, b1, acc[1][1], 0,0,0);
    __syncthreads();
  }
  #pragma unroll
  for (int mf=0; mf<2; mf++)
    #pragma unroll
    for (int nf=0; nf<2; nf++)
      #pragma unroll
      for (int r=0; r<4; r++){
        int m = m0 + wm*32 + mf*16 + quad*4 + r;
        int n = n0 + wn*32 + nf*16 + l16;
        Cp[(size_t)m*Dd+n] = f2b(acc[mf][nf][r]);
      }
}

// ---------------- init: zero state + bf16 snapshots of W1/W2/Wout + barrier ------
__global__ __launch_bounds__(256)
void init_k(Ptrs p){
  size_t i = (size_t)blockIdx.x*256 + threadIdx.x;
  size_t stride = (size_t)gridDim.x*256;
  for (size_t j=i; j<(size_t)Hh*Dd; j+=stride){
    p.Wd1[j]=0.f; p.M1[j]=0.f; p.Wd2[j]=0.f; p.M2[j]=0.f;
    p.e1a[j] = f2b(p.W1[j]);
    p.e2a[j] = f2b(p.W2[j]);
    p.e2Ta[j] = f2b(p.W2[(size_t)(j & (Dd-1))*Hh + (j>>9)]);  // [h][d] = W2[d][h]
  }
  for (size_t j=i; j<(size_t)Dd*Dd; j+=stride) p.woutb[j] = f2b(p.Wout[j]);
  if (i < 16) p.bar[i] = 0u;
}

// ---------------- halo save (last 3 rows of each chunk, pre-conv) ----------------
__global__ void halo_k(const ushort_t* __restrict__ kbuf, const ushort_t* __restrict__ vbuf,
                       const ushort_t* __restrict__ qbuf, ushort_t* __restrict__ halo){
  int bid = blockIdx.x;
  int t = bid / (NCn*Bb);
  int rem = bid % (NCn*Bb);
  int nc = rem / Bb, b = rem % Bb;
  const ushort_t* src = (t==0)?kbuf:((t==1)?vbuf:qbuf);
  ushort_t* dst = halo + (((size_t)t*NCn + nc)*Bb + b)*3*Dd;
  for (int e = threadIdx.x; e < 3*Dd; e += 256){
    int j = e / Dd, d = e % Dd;
    int s = nc*CSc + 61 + j;
    dst[e] = src[((size_t)b*Ss + s)*Dd + d];
  }
}

// ---------------- in-place causal depthwise conv (K=4) ---------------------------
__global__ void conv_k(ushort_t* __restrict__ kbuf, ushort_t* __restrict__ vbuf, ushort_t* __restrict__ qbuf,
                       const float* __restrict__ ckw, const float* __restrict__ ckb,
                       const float* __restrict__ cvw, const float* __restrict__ cvb,
                       const float* __restrict__ cqw, const float* __restrict__ cqb,
                       const ushort_t* __restrict__ halo){
  int bid = blockIdx.x;
  int t = bid / (NCn*Bb);
  int rem = bid % (NCn*Bb);
  int nc = rem / Bb, b = rem % Bb;
  ushort_t* buf = (t==0)?kbuf:((t==1)?vbuf:qbuf);
  const float* cw = (t==0)?ckw:((t==1)?cvw:cqw);
  const float* cb = (t==0)?ckb:((t==1)?cvb:cqb);
  const ushort_t* hl = halo + (((size_t)t*NCn + (nc>0?nc-1:0))*Bb + b)*3*Dd;
  for (int rep=0; rep<2; ++rep){
    int d = threadIdx.x + rep*256;
    float w0 = cw[d*4+0], w1 = cw[d*4+1], w2 = cw[d*4+2], w3 = cw[d*4+3];
    float bias = cb[d];
    float p1, p2, p3;
    if (nc == 0) { p1=p2=p3=0.0f; }
    else { p1 = b2f(hl[2*Dd+d]); p2 = b2f(hl[1*Dd+d]); p3 = b2f(hl[0*Dd+d]); }
    ushort_t* row = buf + ((size_t)b*Ss + nc*CSc)*Dd + d;
    for (int c=0;c<CSc;++c){
      float cur = b2f(row[(size_t)c*Dd]);
      float o = w3*cur + w2*p1 + w1*p2 + w0*p3 + bias;
      p3 = p2; p2 = p1; p1 = cur;
      row[(size_t)c*Dd] = f2b(o);
    }
  }
}

// ---------------- per-chunk scalar gates -----------------------------------------
__global__ __launch_bounds__(256)
void gates_k(const float* __restrict__ x,
             const float* __restrict__ wd, const float* __restrict__ bd,
             const float* __restrict__ wl, const float* __restrict__ bl,
             const float* __restrict__ we, const float* __restrict__ be,
             float* __restrict__ gates){
  int nc = blockIdx.x;
  int wave = threadIdx.x >> 6, lane = threadIdx.x & 63;
  __shared__ float red[4][3];
  float accA=0.f, accL=0.f, accE=0.f;
  float bdv = bd[0], blv = bl[0], bev = be[0];
  for (int pi = wave; pi < Bb*CSc; pi += 4) {
    int b = pi / CSc, c = pi % CSc;
    const float* xr = x + ((size_t)b*Ss + nc*CSc + c)*Dd + lane*8;
    float da=0.f, dl=0.f, de=0.f;
    #pragma unroll
    for (int u=0;u<8;++u){
      float xv = xr[u];
      int d = lane*8+u;
      da += xv*wd[d]; dl += xv*wl[d]; de += xv*we[d];
    }
    #pragma unroll
    for (int off=32; off; off>>=1){
      da += __shfl_down(da, off);
      dl += __shfl_down(dl, off);
      de += __shfl_down(de, off);
    }
    if (lane==0){
      accA += sig_(da + bdv);
      accL += sig_(dl + blv);
      accE += sig_(de + bev);
    }
  }
  if (lane==0){ red[wave][0]=accA; red[wave][1]=accL; red[wave][2]=accE; }
  __syncthreads();
  if (threadIdx.x==0){
    float a=0.f,l=0.f,e=0.f;
    for (int w=0;w<4;w++){ a+=red[w][0]; l+=red[w][1]; e+=red[w][2]; }
    gates[nc]        = a*(1.0f/512.0f);
    gates[NCn+nc]    = l*(1.0f/512.0f);
    gates[2*NCn+nc]  = e*(1.0f/512.0f);
  }
}

extern "C" void kernel_launch(void* const* d_in, const int* in_sizes, int n_in,
                              void* d_out, int out_size, void* d_ws, size_t ws_size,
                              hipStream_t stream) {
  (void)in_sizes; (void)n_in; (void)out_size;
  const float* x       = (const float*)d_in[0];
  const float* Wk      = (const float*)d_in[1];
  const float* Wv      = (const float*)d_in[2];
  const float* Wq      = (const float*)d_in[3];
  const float* Wout    = (const float*)d_in[4];
  const float* ckw     = (const float*)d_in[5];
  const float* ckb     = (const float*)d_in[6];
  const float* cvw     = (const float*)d_in[7];
  const float* cvb     = (const float*)d_in[8];
  const float* cqw     = (const float*)d_in[9];
  const float* cqb     = (const float*)d_in[10];
  const float* w_decay = (const float*)d_in[11];
  const float* b_decay = (const float*)d_in[12];
  const float* w_lr    = (const float*)d_in[13];
  const float* b_lr    = (const float*)d_in[14];
  const float* w_eta   = (const float*)d_in[15];
  const float* b_eta   = (const float*)d_in[16];
  const float* W1      = (const float*)d_in[17];
  const float* W2      = (const float*)d_in[18];

  char* base = (char*)d_ws;
  size_t off = 0;
  auto alloc_f = [&](size_t n)->float*   { float* r=(float*)(base+off);   off += n*4; return r; };
  auto alloc_u = [&](size_t n)->unsigned*{ unsigned* r=(unsigned*)(base+off); off += n*4; return r; };
  auto alloc_b = [&](size_t n)->ushort_t*{ ushort_t* r=(ushort_t*)(base+off); off += n*2; off=(off+15)&~15ull; return r; };

  float* Wd1  = alloc_f((size_t)Hh*Dd);
  float* Wd2  = alloc_f((size_t)Dd*Hh);
  float* M1   = alloc_f((size_t)Hh*Dd);
  float* M2   = alloc_f((size_t)Dd*Hh);
  float* gates= alloc_f(3*NCn + 4);
  unsigned* bar = alloc_u(64);

  const size_t BSD = (size_t)Bb*Ss*Dd;
  ushort_t* kbuf = alloc_b(BSD);
  ushort_t* vbuf = alloc_b(BSD);
  ushort_t* qbuf = alloc_b(BSD);
  ushort_t* halo = alloc_b((size_t)3*NCn*Bb*3*Dd);
  ushort_t* h1   = alloc_b((size_t)MROW*Hh);
  ushort_t* a1   = alloc_b((size_t)MROW*Hh);
  ushort_t* d1b  = alloc_b((size_t)MROW*Hh);
  ushort_t* d2b  = alloc_b((size_t)MROW*Dd);
  ushort_t* rbuf = alloc_b((size_t)MROW*Dd);
  ushort_t* e1a  = alloc_b((size_t)Hh*Dd);
  ushort_t* e1b  = alloc_b((size_t)Hh*Dd);
  ushort_t* e2a  = alloc_b((size_t)Dd*Hh);
  ushort_t* e2b  = alloc_b((size_t)Dd*Hh);
  ushort_t* e2Ta = alloc_b((size_t)Hh*Dd);
  ushort_t* e2Tb = alloc_b((size_t)Hh*Dd);
  ushort_t* woutb= alloc_b((size_t)Dd*Dd);

  if (ws_size < off) return;  // clean fail instead of fault

  Ptrs p;
  p.x=x; p.Wk=Wk; p.Wv=Wv; p.Wq=Wq; p.Wout=Wout; p.W1=W1; p.W2=W2;
  p.kbuf=kbuf; p.vbuf=vbuf; p.qbuf=qbuf; p.rbuf=rbuf;
  p.h1=h1; p.a1=a1; p.d1b=d1b; p.d2b=d2b;
  p.e1a=e1a; p.e1b=e1b; p.e2a=e2a; p.e2b=e2b; p.e2Ta=e2Ta; p.e2Tb=e2Tb; p.woutb=woutb;
  p.Wd1=Wd1; p.Wd2=Wd2; p.M1=M1; p.M2=M2;
  p.gates=gates; p.bar=bar; p.out=(float*)d_out;

  init_k<<<1024, 256, 0, stream>>>(p);
  gk_proj<<<dim3(Bb*Ss/64, Dd/64, 3), 256, 0, stream>>>(p);
  halo_k<<<3*NCn*Bb, 256, 0, stream>>>(kbuf, vbuf, qbuf, halo);
  conv_k<<<3*NCn*Bb, 256, 0, stream>>>(kbuf, vbuf, qbuf, ckw, ckb, cvw, cvb, cqw, cqb, halo);
  gates_k<<<NCn, 256, 0, stream>>>(x, w_decay, b_decay, w_lr, b_lr, w_eta, b_eta, gates);

  // whole 64-chunk scan: one cooperative launch, custom agent-scope barriers
  void* args[] = { (void*)&p };
  hipLaunchCooperativeKernel((void*)scan_k, dim3(NB), dim3(512), args, 0, stream);
}